// Round 6
// baseline (3826.530 us; speedup 1.0000x reference)
//
#include <hip/hip_runtime.h>
#include <stdint.h>

#define N_EDGES 2000000
#define NUM_SEG 500000
#define HID 128
#define NBLK 4

typedef __attribute__((ext_vector_type(8))) unsigned short ushort8;
typedef __attribute__((ext_vector_type(8))) __bf16 bf16x8;
typedef __attribute__((ext_vector_type(4))) float float4v;
typedef __attribute__((ext_vector_type(2))) uint32_t uint2v;

__device__ inline unsigned short f32_to_bf16(float f) {
    return __builtin_bit_cast(unsigned short, (__bf16)f);   // native cvt, RNE
}

__device__ inline uint32_t pack_bf16(float lo, float hi) {
#if __has_builtin(__builtin_amdgcn_cvt_pk_bf16_f32)
    typedef __attribute__((ext_vector_type(2))) __bf16 bf16x2;
    bf16x2 r = __builtin_amdgcn_cvt_pk_bf16_f32(lo, hi);
    return __builtin_bit_cast(uint32_t, r);
#else
    return (uint32_t)f32_to_bf16(lo) | ((uint32_t)f32_to_bf16(hi) << 16);
#endif
}

// ---- prep: WbF[blk] = bf16(W_res*rms_w) in A-FRAGMENT ORDER:
//   i = blk*16384 + (kt*8+ft)*512 + lane*8 + j -> W'[m=ft*16+(lane&15)][k=kt*32+(lane>>4)*8+j]
// Also packs Win4[f] = {W_in[f][0..2], b_in[f]} and zero-fills segsum.
__global__ void prep_kernel(const float* __restrict__ W_res,
                            const float* __restrict__ rms_w,
                            const float* __restrict__ W_in,
                            const float* __restrict__ b_in,
                            unsigned short* __restrict__ WbF,
                            float* __restrict__ Win4,
                            float* __restrict__ segsum) {
    int i = blockIdx.x * 256 + threadIdx.x;
    if (i < 65536) {
        int blk = i >> 14;
        int r = i & 16383;
        int j = r & 7, lane = (r >> 3) & 63, ft = (r >> 9) & 7, kt = r >> 12;
        int cc = lane & 15, qq = lane >> 4;
        int row = ft * 16 + cc;
        int k = kt * 32 + qq * 8 + j;
        WbF[i] = f32_to_bf16(W_res[blk * 16384 + row * HID + k] * rms_w[blk * HID + k]);
    } else if (i < 65536 + 128) {
        int f = i - 65536;
        Win4[f * 4 + 0] = W_in[f * 3 + 0];
        Win4[f * 4 + 1] = W_in[f * 3 + 1];
        Win4[f * 4 + 2] = W_in[f * 3 + 2];
        Win4[f * 4 + 3] = b_in[f];
    } else {
        int s = i - 65536 - 128;
        if (s < NUM_SEG) segsum[s] = 0.0f;
    }
}

// ---- fused MLP: 128 rows/wg, 4 waves x 32 rows, h in D[f][r] layout registers.
// W staged K-half at a time via async global_load_lds (Wlo/Whi ping-pong across the
// two per-block barriers); hnF is 4KB/wave, slots reused between K-halves.
// Register discipline for 3 waves/SIMD: blk loop unroll(1), stage-1/epilogue unroll(2).
__global__ __launch_bounds__(256, 3)
void mlp_kernel(const float* __restrict__ x,           // [N,3]
                const unsigned short* __restrict__ WbF,// [4,16384] bf16 A-frag order
                const float* __restrict__ b_res,       // [4,128]
                const float* __restrict__ W_out,       // [128]
                const float* __restrict__ b_out,       // [1]
                const float* __restrict__ Win4g,       // [128,4] = {w0,w1,w2,b_in}
                float* __restrict__ e) {               // [N] = exp(logit)
    __shared__ __align__(16) unsigned short Wlo[8192];  // 16 KB: kt 0,1 A-frags
    __shared__ __align__(16) unsigned short Whi[8192];  // 16 KB: kt 2,3 A-frags
    __shared__ __align__(16) unsigned short hnF[8192];  // 16 KB: 4 KB/wave B-frags
    __shared__ __align__(16) float4v Win4s[128];        // 2 KB
    __shared__ float xs[384];

    const int t = threadIdx.x;
    const int wave = t >> 6;
    const int lane = t & 63;
    const int q = lane >> 4;   // quad within wave
    const int c = lane & 15;   // lane within quad
    const long rowbase = (long)blockIdx.x * 128;

    // async 16KB W-half load: 4 waves x 4 issues x 1KB (lds dest = uniform base + lane*16B)
    #define LOAD_HALF(gbase, ldsarr)                                                      \
        {                                                                                 \
            const unsigned short* _g = (gbase);                                           \
            _Pragma("unroll")                                                             \
            for (int _i = 0; _i < 4; ++_i) {                                              \
                __builtin_amdgcn_global_load_lds(                                         \
                    (const __attribute__((address_space(1))) uint32_t*)                   \
                        (_g + (wave * 4 + _i) * 512 + lane * 8),                          \
                    (__attribute__((address_space(3))) uint32_t*)                         \
                        (&(ldsarr)[(wave * 4 + _i) * 512]),                               \
                    16, 0, 0);                                                            \
            }                                                                             \
        }

    LOAD_HALF(WbF, Wlo);                              // blk0 lo in flight
    for (int i = t; i < 384; i += 256) xs[i] = x[rowbase * 3 + i];
    if (t < 128) Win4s[t] = ((const float4v*)Win4g)[t];
    __syncthreads();                                  // drains lo0 + xs + Win4s
    LOAD_HALF(WbF + 8192, Whi);                       // blk0 hi in flight during stage-1

    // ---- stage 1: h0[f][r] = W_in[f].x[r] + b_in[f]
    float4v h[8][2];   // [ft][rt], component = reg; f=ft*16+q*4+reg, r=wave*32+rt*16+c
    {
        float xr[2][3];
        #pragma unroll
        for (int rt = 0; rt < 2; ++rt)
            #pragma unroll
            for (int k = 0; k < 3; ++k)
                xr[rt][k] = xs[(wave * 32 + rt * 16 + c) * 3 + k];
        #pragma unroll 2
        for (int ft = 0; ft < 8; ++ft)
            #pragma unroll
            for (int reg = 0; reg < 4; ++reg) {
                float4v wb = Win4s[ft * 16 + q * 4 + reg];
                #pragma unroll
                for (int rt = 0; rt < 2; ++rt)
                    h[ft][rt][reg] = wb.w + xr[rt][0] * wb.x + xr[rt][1] * wb.y + xr[rt][2] * wb.z;
            }
    }

    // hnF addressing: frag slot s=(kt&1)*2+rt (512 shorts each), 4 slots/wave, reused per half
    const int whbase = wave * 2048 + (q >> 1) * 128 + c * 8 + (q & 1) * 4;  // write base
    const int rbase = wave * 2048 + lane * 8;                                // read base

    #pragma unroll 1
    for (int blk = 0; blk < NBLK; ++blk) {
        float4v acc[8][2];
        float rs[2];

        // ======== LO half: kt 0,1  (B-frags from ft 0..3) ========
        #pragma unroll
        for (int ft = 0; ft < 4; ++ft) {
            const int foff = ((ft >> 1) & 1) * 1024 + (ft & 1) * 256;
            #pragma unroll
            for (int rt = 0; rt < 2; ++rt) {
                uint2v v;
                v.x = pack_bf16(h[ft][rt][0], h[ft][rt][1]);
                v.y = pack_bf16(h[ft][rt][2], h[ft][rt][3]);
                *(uint2v*)&hnF[whbase + foff + rt * 512] = v;
            }
        }
        // rmsnorm scale (full h is live; off the LDS critical path)
        #pragma unroll
        for (int rt = 0; rt < 2; ++rt) {
            float ss = 0.0f;
            #pragma unroll
            for (int ft = 0; ft < 8; ++ft)
                #pragma unroll
                for (int reg = 0; reg < 4; ++reg) { float vv = h[ft][rt][reg]; ss += vv * vv; }
            ss += __shfl_xor(ss, 16, 64);
            ss += __shfl_xor(ss, 32, 64);
            rs[rt] = rsqrtf(ss * (1.0f / 128.0f) + 1.1920929e-7f);
        }
        // MFMA kt=0 (C=0 peel) and kt=1 from Wlo
        {
            bf16x8 b0 = __builtin_bit_cast(bf16x8, *(const ushort8*)&hnF[rbase + 0 * 512]);
            bf16x8 b1 = __builtin_bit_cast(bf16x8, *(const ushort8*)&hnF[rbase + 1 * 512]);
            const float4v zero4 = {0.0f, 0.0f, 0.0f, 0.0f};
            #pragma unroll
            for (int ft = 0; ft < 8; ++ft) {
                bf16x8 a = __builtin_bit_cast(bf16x8, *(const ushort8*)&Wlo[ft * 512 + lane * 8]);
                acc[ft][0] = __builtin_amdgcn_mfma_f32_16x16x32_bf16(a, b0, zero4, 0, 0, 0);
                acc[ft][1] = __builtin_amdgcn_mfma_f32_16x16x32_bf16(a, b1, zero4, 0, 0, 0);
            }
            bf16x8 b2 = __builtin_bit_cast(bf16x8, *(const ushort8*)&hnF[rbase + 2 * 512]);
            bf16x8 b3 = __builtin_bit_cast(bf16x8, *(const ushort8*)&hnF[rbase + 3 * 512]);
            #pragma unroll
            for (int ft = 0; ft < 8; ++ft) {
                bf16x8 a = __builtin_bit_cast(bf16x8,
                    *(const ushort8*)&Wlo[(8 + ft) * 512 + lane * 8]);
                acc[ft][0] = __builtin_amdgcn_mfma_f32_16x16x32_bf16(a, b2, acc[ft][0], 0, 0, 0);
                acc[ft][1] = __builtin_amdgcn_mfma_f32_16x16x32_bf16(a, b3, acc[ft][1], 0, 0, 0);
            }
        }
        __syncthreads();   // Wlo readers done; drains Whi(blk) issued one half earlier
        if (blk < NBLK - 1) LOAD_HALF(WbF + (blk + 1) * 16384, Wlo);

        // ======== HI half: kt 2,3  (B-frags from ft 4..7, slots reused) ========
        #pragma unroll
        for (int ft = 4; ft < 8; ++ft) {
            const int foff = ((ft >> 1) & 1) * 1024 + (ft & 1) * 256;
            #pragma unroll
            for (int rt = 0; rt < 2; ++rt) {
                uint2v v;
                v.x = pack_bf16(h[ft][rt][0], h[ft][rt][1]);
                v.y = pack_bf16(h[ft][rt][2], h[ft][rt][3]);
                *(uint2v*)&hnF[whbase + foff + rt * 512] = v;
            }
        }
        {
            bf16x8 b0 = __builtin_bit_cast(bf16x8, *(const ushort8*)&hnF[rbase + 0 * 512]);
            bf16x8 b1 = __builtin_bit_cast(bf16x8, *(const ushort8*)&hnF[rbase + 1 * 512]);
            #pragma unroll
            for (int ft = 0; ft < 8; ++ft) {
                bf16x8 a = __builtin_bit_cast(bf16x8, *(const ushort8*)&Whi[ft * 512 + lane * 8]);
                acc[ft][0] = __builtin_amdgcn_mfma_f32_16x16x32_bf16(a, b0, acc[ft][0], 0, 0, 0);
                acc[ft][1] = __builtin_amdgcn_mfma_f32_16x16x32_bf16(a, b1, acc[ft][1], 0, 0, 0);
            }
            bf16x8 b2 = __builtin_bit_cast(bf16x8, *(const ushort8*)&hnF[rbase + 2 * 512]);
            bf16x8 b3 = __builtin_bit_cast(bf16x8, *(const ushort8*)&hnF[rbase + 3 * 512]);
            #pragma unroll
            for (int ft = 0; ft < 8; ++ft) {
                bf16x8 a = __builtin_bit_cast(bf16x8,
                    *(const ushort8*)&Whi[(8 + ft) * 512 + lane * 8]);
                acc[ft][0] = __builtin_amdgcn_mfma_f32_16x16x32_bf16(a, b2, acc[ft][0], 0, 0, 0);
                acc[ft][1] = __builtin_amdgcn_mfma_f32_16x16x32_bf16(a, b3, acc[ft][1], 0, 0, 0);
            }
        }
        // epilogue: h += relu(rs[rt]*acc + b_res[f])  (unroll 2: bb temps bounded)
        {
            const float4v* br4 = (const float4v*)(b_res + blk * HID);
            #pragma unroll 2
            for (int ft = 0; ft < 8; ++ft) {
                float4v bb = br4[ft * 4 + q];
                #pragma unroll
                for (int rt = 0; rt < 2; ++rt)
                    #pragma unroll
                    for (int reg = 0; reg < 4; ++reg)
                        h[ft][rt][reg] += fmaxf(fmaf(rs[rt], acc[ft][rt][reg], bb[reg]), 0.0f);
            }
        }
        __syncthreads();   // Whi readers done; drains Wlo(blk+1) issued one half earlier
        if (blk < NBLK - 1) LOAD_HALF(WbF + (blk + 1) * 16384 + 8192, Whi);
    }

    // ---- output head: e[r] = exp(h[.][r] . W_out + b_out)
    const float bo = b_out[0];
    const float4v* wo4 = (const float4v*)W_out;
    float s[2] = {0.0f, 0.0f};
    #pragma unroll 2
    for (int ft = 0; ft < 8; ++ft) {
        float4v w = wo4[ft * 4 + q];
        #pragma unroll
        for (int rt = 0; rt < 2; ++rt)
            #pragma unroll
            for (int reg = 0; reg < 4; ++reg)
                s[rt] += h[ft][rt][reg] * w[reg];
    }
    #pragma unroll
    for (int rt = 0; rt < 2; ++rt) {
        s[rt] += __shfl_xor(s[rt], 16, 64);
        s[rt] += __shfl_xor(s[rt], 32, 64);
    }
    if (q == 0) {
        #pragma unroll
        for (int rt = 0; rt < 2; ++rt)
            e[rowbase + wave * 32 + rt * 16 + c] = __expf(s[rt] + bo);
    }
}

// ---- segment sum of e (sorted ids): wave-level segmented scan, tail lanes atomicAdd
__global__ void segsum_kernel(const float* __restrict__ e, const int* __restrict__ ids,
                              float* __restrict__ segsum) {
    int i = blockIdx.x * 256 + threadIdx.x;
    int lane = threadIdx.x & 63;
    float v = 0.0f; int id = -1;
    if (i < N_EDGES) { v = e[i]; id = ids[i]; }
    #pragma unroll
    for (int d = 1; d < 64; d <<= 1) {
        float ov = __shfl_up(v, d, 64);
        int oid = __shfl_up(id, d, 64);
        if (lane >= d && oid == id) v += ov;
    }
    int nid = __shfl_down(id, 1, 64);
    bool tail = (lane == 63) || (nid != id);
    if (id >= 0 && tail) atomicAdd(&segsum[id], v);
}

__global__ void norm_kernel(const float* __restrict__ e, const int* __restrict__ ids,
                            const float* __restrict__ segsum, float* __restrict__ out) {
    int i = blockIdx.x * 256 + threadIdx.x;
    if (i < N_EDGES) out[i] = e[i] / segsum[ids[i]];
}

extern "C" void kernel_launch(void* const* d_in, const int* in_sizes, int n_in,
                              void* d_out, int out_size, void* d_ws, size_t ws_size,
                              hipStream_t stream) {
    const float* x      = (const float*)d_in[0];
    const int*   ids    = (const int*)d_in[1];
    const float* W_in   = (const float*)d_in[2];
    const float* b_in   = (const float*)d_in[3];
    const float* rms_w  = (const float*)d_in[4];
    const float* W_res  = (const float*)d_in[5];
    const float* b_res  = (const float*)d_in[6];
    const float* W_out  = (const float*)d_in[7];
    const float* b_out  = (const float*)d_in[8];
    float* out = (float*)d_out;

    char* ws = (char*)d_ws;
    unsigned short* WbF = (unsigned short*)ws;                 // 131072 B
    float* Win4   = (float*)(ws + 131072);                     // 2048 B
    float* e      = (float*)(ws + 131072 + 2048);              // 8,000,000 B
    float* segsum = (float*)(ws + 131072 + 2048 + 8000000);    // 2,000,000 B

    int prep_items = 65536 + 128 + NUM_SEG;
    prep_kernel<<<(prep_items + 255) / 256, 256, 0, stream>>>(W_res, rms_w, W_in, b_in,
                                                              WbF, Win4, segsum);
    mlp_kernel<<<N_EDGES / 128, 256, 0, stream>>>(x, WbF, b_res, W_out, b_out, Win4, e);
    segsum_kernel<<<(N_EDGES + 255) / 256, 256, 0, stream>>>(e, ids, segsum);
    norm_kernel<<<(N_EDGES + 255) / 256, 256, 0, stream>>>(e, ids, segsum, out);
}

// Round 7
// 2026.472 us; speedup vs baseline: 1.8883x; 1.8883x over previous
//
#include <hip/hip_runtime.h>
#include <stdint.h>

#define N_EDGES 2000000
#define NUM_SEG 500000
#define HID 128
#define NBLK 4

typedef __attribute__((ext_vector_type(8))) unsigned short ushort8;
typedef __attribute__((ext_vector_type(8))) __bf16 bf16x8;
typedef __attribute__((ext_vector_type(4))) float float4v;
typedef __attribute__((ext_vector_type(2))) uint32_t uint2v;

__device__ inline unsigned short f32_to_bf16(float f) {
    return __builtin_bit_cast(unsigned short, (__bf16)f);   // native cvt, RNE
}

__device__ inline uint32_t pack_bf16(float lo, float hi) {
#if __has_builtin(__builtin_amdgcn_cvt_pk_bf16_f32)
    typedef __attribute__((ext_vector_type(2))) __bf16 bf16x2;
    bf16x2 r = __builtin_amdgcn_cvt_pk_bf16_f32(lo, hi);
    return __builtin_bit_cast(uint32_t, r);
#else
    return (uint32_t)f32_to_bf16(lo) | ((uint32_t)f32_to_bf16(hi) << 16);
#endif
}

// ---- prep: WbF[blk] = bf16(W_res*rms_w) in FT-HALF-MAJOR A-FRAGMENT ORDER:
//   i = blk*16384 + half*8192 + (kt*4+ftp)*512 + lane*8 + j
//   -> W'[row = half*64 + ftp*16 + (lane&15)][k = kt*32 + (lane>>4)*8 + j]
// Also packs Win4[f] = {W_in[f][0..2], b_in[f]} and zero-fills segsum.
__global__ void prep_kernel(const float* __restrict__ W_res,
                            const float* __restrict__ rms_w,
                            const float* __restrict__ W_in,
                            const float* __restrict__ b_in,
                            unsigned short* __restrict__ WbF,
                            float* __restrict__ Win4,
                            float* __restrict__ segsum) {
    int i = blockIdx.x * 256 + threadIdx.x;
    if (i < 65536) {
        int blk = i >> 14;
        int r = i & 16383;
        int half = r >> 13;
        int r2 = r & 8191;
        int kt = r2 >> 11, ftp = (r2 >> 9) & 3, lane = (r2 >> 3) & 63, j = r2 & 7;
        int row = half * 64 + ftp * 16 + (lane & 15);
        int k = kt * 32 + (lane >> 4) * 8 + j;
        WbF[i] = f32_to_bf16(W_res[blk * 16384 + row * HID + k] * rms_w[blk * HID + k]);
    } else if (i < 65536 + 128) {
        int f = i - 65536;
        Win4[f * 4 + 0] = W_in[f * 3 + 0];
        Win4[f * 4 + 1] = W_in[f * 3 + 1];
        Win4[f * 4 + 2] = W_in[f * 3 + 2];
        Win4[f * 4 + 3] = b_in[f];
    } else {
        int s = i - 65536 - 128;
        if (s < NUM_SEG) segsum[s] = 0.0f;
    }
}

// ---- fused MLP: 128 rows/wg, 4 waves x 32 rows, h in D[f][r] registers.
// acc computed per ft-HALF (32 regs live instead of 64) so h+acc fits 3 waves/SIMD.
// W staged one ft-half (16 KB, all kt) at a time via async global_load_lds into a
// single Wbuf; 4 barriers/block. hnF (all kt) is 8 KB/wave, per-wave private.
__global__ __launch_bounds__(256, 3)
void mlp_kernel(const float* __restrict__ x,           // [N,3]
                const unsigned short* __restrict__ WbF,// [4][2][8192] bf16 frag order
                const float* __restrict__ b_res,       // [4,128]
                const float* __restrict__ W_out,       // [128]
                const float* __restrict__ b_out,       // [1]
                const float* __restrict__ Win4g,       // [128,4] = {w0,w1,w2,b_in}
                float* __restrict__ e) {               // [N] = exp(logit)
    __shared__ __align__(16) unsigned short Wbuf[8192];   // 16 KB: one ft-half, all kt
    __shared__ __align__(16) unsigned short hnF[16384];   // 32 KB: 8 KB/wave B-frags
    __shared__ __align__(16) float4v Win4s[128];          // 2 KB
    __shared__ float xs[384];                             // 1.5 KB

    const int t = threadIdx.x;
    const int wave = t >> 6;
    const int lane = t & 63;
    const int q = lane >> 4;   // quad within wave
    const int c = lane & 15;   // lane within quad
    const long rowbase = (long)blockIdx.x * 128;

    // async 16KB load into Wbuf: 4 waves x 4 issues x 1KB (lds dest wave-uniform + lane*16B)
    #define LOAD_HALF(gbase)                                                              \
        {                                                                                 \
            const unsigned short* _g = (gbase);                                           \
            _Pragma("unroll")                                                             \
            for (int _i = 0; _i < 4; ++_i) {                                              \
                __builtin_amdgcn_global_load_lds(                                         \
                    (const __attribute__((address_space(1))) uint32_t*)                   \
                        (_g + (wave * 4 + _i) * 512 + lane * 8),                          \
                    (__attribute__((address_space(3))) uint32_t*)                         \
                        (&Wbuf[(wave * 4 + _i) * 512]),                                   \
                    16, 0, 0);                                                            \
            }                                                                             \
        }

    LOAD_HALF(WbF);                                   // blk0 half0 in flight
    for (int i = t; i < 384; i += 256) xs[i] = x[rowbase * 3 + i];
    if (t < 128) Win4s[t] = ((const float4v*)Win4g)[t];
    __syncthreads();                                  // xs/Win4s ready + half0 drained

    // ---- stage 1: h0[f][r] = W_in[f].x[r] + b_in[f]
    float4v h[8][2];   // [ft][rt]; f = ft*16+q*4+reg, r = wave*32+rt*16+c
    {
        float xr[2][3];
        #pragma unroll
        for (int rt = 0; rt < 2; ++rt)
            #pragma unroll
            for (int k = 0; k < 3; ++k)
                xr[rt][k] = xs[(wave * 32 + rt * 16 + c) * 3 + k];
        #pragma unroll 2
        for (int ft = 0; ft < 8; ++ft)
            #pragma unroll
            for (int reg = 0; reg < 4; ++reg) {
                float4v wb = Win4s[ft * 16 + q * 4 + reg];
                #pragma unroll
                for (int rt = 0; rt < 2; ++rt)
                    h[ft][rt][reg] = wb.w + xr[rt][0] * wb.x + xr[rt][1] * wb.y + xr[rt][2] * wb.z;
            }
    }

    // hnF: 8 slots/wave (kt*2+rt), 512 shorts each; per-wave private (no barrier needed)
    const int whbase = wave * 4096 + (q >> 1) * 128 + c * 8 + (q & 1) * 4;  // write base
    const int rbase  = wave * 4096 + lane * 8;                               // read base

    #pragma unroll 1
    for (int blk = 0; blk < NBLK; ++blk) {
        // ---- block start: stage full h into hnF (pre-update values), compute rs
        #pragma unroll
        for (int ft = 0; ft < 8; ++ft) {
            const int foff = (ft >> 1) * 1024 + (ft & 1) * 256;
            #pragma unroll
            for (int rt = 0; rt < 2; ++rt) {
                uint2v v;
                v.x = pack_bf16(h[ft][rt][0], h[ft][rt][1]);
                v.y = pack_bf16(h[ft][rt][2], h[ft][rt][3]);
                *(uint2v*)&hnF[whbase + foff + rt * 512] = v;
            }
        }
        float rs[2];
        #pragma unroll
        for (int rt = 0; rt < 2; ++rt) {
            float ss = 0.0f;
            #pragma unroll
            for (int ft = 0; ft < 8; ++ft)
                #pragma unroll
                for (int reg = 0; reg < 4; ++reg) { float vv = h[ft][rt][reg]; ss += vv * vv; }
            ss += __shfl_xor(ss, 16, 64);
            ss += __shfl_xor(ss, 32, 64);
            rs[rt] = rsqrtf(ss * (1.0f / 128.0f) + 1.1920929e-7f);
        }
        __syncthreads();   // (c) Wbuf = this block's ft-half0, fully landed

        // ======== ft-half 0: features 0..63 ========
        {
            float4v acc[4][2];
            #pragma unroll
            for (int kt = 0; kt < 4; ++kt) {
                bf16x8 b0 = __builtin_bit_cast(bf16x8, *(const ushort8*)&hnF[rbase + (kt * 2 + 0) * 512]);
                bf16x8 b1 = __builtin_bit_cast(bf16x8, *(const ushort8*)&hnF[rbase + (kt * 2 + 1) * 512]);
                if (kt == 0) {
                    const float4v zero4 = {0.0f, 0.0f, 0.0f, 0.0f};
                    #pragma unroll
                    for (int ftp = 0; ftp < 4; ++ftp) {
                        bf16x8 a = __builtin_bit_cast(bf16x8, *(const ushort8*)&Wbuf[ftp * 512 + lane * 8]);
                        acc[ftp][0] = __builtin_amdgcn_mfma_f32_16x16x32_bf16(a, b0, zero4, 0, 0, 0);
                        acc[ftp][1] = __builtin_amdgcn_mfma_f32_16x16x32_bf16(a, b1, zero4, 0, 0, 0);
                    }
                } else {
                    #pragma unroll
                    for (int ftp = 0; ftp < 4; ++ftp) {
                        bf16x8 a = __builtin_bit_cast(bf16x8,
                            *(const ushort8*)&Wbuf[(kt * 4 + ftp) * 512 + lane * 8]);
                        acc[ftp][0] = __builtin_amdgcn_mfma_f32_16x16x32_bf16(a, b0, acc[ftp][0], 0, 0, 0);
                        acc[ftp][1] = __builtin_amdgcn_mfma_f32_16x16x32_bf16(a, b1, acc[ftp][1], 0, 0, 0);
                    }
                }
            }
            __syncthreads();   // (e) half0 readers done
            LOAD_HALF(WbF + blk * 16384 + 8192);   // ft-half1 in flight
            // epilogue half0 (VALU only — covers the load)
            const float4v* br4 = (const float4v*)(b_res + blk * HID);
            #pragma unroll
            for (int ftp = 0; ftp < 4; ++ftp) {
                float4v bb = br4[ftp * 4 + q];
                #pragma unroll
                for (int rt = 0; rt < 2; ++rt)
                    #pragma unroll
                    for (int reg = 0; reg < 4; ++reg)
                        h[ftp][rt][reg] += fmaxf(fmaf(rs[rt], acc[ftp][rt][reg], bb[reg]), 0.0f);
            }
        }
        __syncthreads();   // (g) half1 landed

        // ======== ft-half 1: features 64..127 ========
        {
            float4v acc[4][2];
            #pragma unroll
            for (int kt = 0; kt < 4; ++kt) {
                bf16x8 b0 = __builtin_bit_cast(bf16x8, *(const ushort8*)&hnF[rbase + (kt * 2 + 0) * 512]);
                bf16x8 b1 = __builtin_bit_cast(bf16x8, *(const ushort8*)&hnF[rbase + (kt * 2 + 1) * 512]);
                if (kt == 0) {
                    const float4v zero4 = {0.0f, 0.0f, 0.0f, 0.0f};
                    #pragma unroll
                    for (int ftp = 0; ftp < 4; ++ftp) {
                        bf16x8 a = __builtin_bit_cast(bf16x8, *(const ushort8*)&Wbuf[ftp * 512 + lane * 8]);
                        acc[ftp][0] = __builtin_amdgcn_mfma_f32_16x16x32_bf16(a, b0, zero4, 0, 0, 0);
                        acc[ftp][1] = __builtin_amdgcn_mfma_f32_16x16x32_bf16(a, b1, zero4, 0, 0, 0);
                    }
                } else {
                    #pragma unroll
                    for (int ftp = 0; ftp < 4; ++ftp) {
                        bf16x8 a = __builtin_bit_cast(bf16x8,
                            *(const ushort8*)&Wbuf[(kt * 4 + ftp) * 512 + lane * 8]);
                        acc[ftp][0] = __builtin_amdgcn_mfma_f32_16x16x32_bf16(a, b0, acc[ftp][0], 0, 0, 0);
                        acc[ftp][1] = __builtin_amdgcn_mfma_f32_16x16x32_bf16(a, b1, acc[ftp][1], 0, 0, 0);
                    }
                }
            }
            // epilogue half1
            const float4v* br4 = (const float4v*)(b_res + blk * HID);
            #pragma unroll
            for (int ftp = 0; ftp < 4; ++ftp) {
                float4v bb = br4[(4 + ftp) * 4 + q];
                #pragma unroll
                for (int rt = 0; rt < 2; ++rt)
                    #pragma unroll
                    for (int reg = 0; reg < 4; ++reg)
                        h[4 + ftp][rt][reg] += fmaxf(fmaf(rs[rt], acc[ftp][rt][reg], bb[reg]), 0.0f);
            }
        }
        __syncthreads();   // (i) half1 readers done
        if (blk < NBLK - 1) LOAD_HALF(WbF + (blk + 1) * 16384);   // next half0 in flight
    }

    // ---- output head: e[r] = exp(h[.][r] . W_out + b_out)
    const float bo = b_out[0];
    const float4v* wo4 = (const float4v*)W_out;
    float s[2] = {0.0f, 0.0f};
    #pragma unroll 2
    for (int ft = 0; ft < 8; ++ft) {
        float4v w = wo4[ft * 4 + q];
        #pragma unroll
        for (int rt = 0; rt < 2; ++rt)
            #pragma unroll
            for (int reg = 0; reg < 4; ++reg)
                s[rt] += h[ft][rt][reg] * w[reg];
    }
    #pragma unroll
    for (int rt = 0; rt < 2; ++rt) {
        s[rt] += __shfl_xor(s[rt], 16, 64);
        s[rt] += __shfl_xor(s[rt], 32, 64);
    }
    if (q == 0) {
        #pragma unroll
        for (int rt = 0; rt < 2; ++rt)
            e[rowbase + wave * 32 + rt * 16 + c] = __expf(s[rt] + bo);
    }
}

// ---- segment sum of e (sorted ids): wave-level segmented scan, tail lanes atomicAdd
__global__ void segsum_kernel(const float* __restrict__ e, const int* __restrict__ ids,
                              float* __restrict__ segsum) {
    int i = blockIdx.x * 256 + threadIdx.x;
    int lane = threadIdx.x & 63;
    float v = 0.0f; int id = -1;
    if (i < N_EDGES) { v = e[i]; id = ids[i]; }
    #pragma unroll
    for (int d = 1; d < 64; d <<= 1) {
        float ov = __shfl_up(v, d, 64);
        int oid = __shfl_up(id, d, 64);
        if (lane >= d && oid == id) v += ov;
    }
    int nid = __shfl_down(id, 1, 64);
    bool tail = (lane == 63) || (nid != id);
    if (id >= 0 && tail) atomicAdd(&segsum[id], v);
}

__global__ void norm_kernel(const float* __restrict__ e, const int* __restrict__ ids,
                            const float* __restrict__ segsum, float* __restrict__ out) {
    int i = blockIdx.x * 256 + threadIdx.x;
    if (i < N_EDGES) out[i] = e[i] / segsum[ids[i]];
}

extern "C" void kernel_launch(void* const* d_in, const int* in_sizes, int n_in,
                              void* d_out, int out_size, void* d_ws, size_t ws_size,
                              hipStream_t stream) {
    const float* x      = (const float*)d_in[0];
    const int*   ids    = (const int*)d_in[1];
    const float* W_in   = (const float*)d_in[2];
    const float* b_in   = (const float*)d_in[3];
    const float* rms_w  = (const float*)d_in[4];
    const float* W_res  = (const float*)d_in[5];
    const float* b_res  = (const float*)d_in[6];
    const float* W_out  = (const float*)d_in[7];
    const float* b_out  = (const float*)d_in[8];
    float* out = (float*)d_out;

    char* ws = (char*)d_ws;
    unsigned short* WbF = (unsigned short*)ws;                 // 131072 B
    float* Win4   = (float*)(ws + 131072);                     // 2048 B
    float* e      = (float*)(ws + 131072 + 2048);              // 8,000,000 B
    float* segsum = (float*)(ws + 131072 + 2048 + 8000000);    // 2,000,000 B

    int prep_items = 65536 + 128 + NUM_SEG;
    prep_kernel<<<(prep_items + 255) / 256, 256, 0, stream>>>(W_res, rms_w, W_in, b_in,
                                                              WbF, Win4, segsum);
    mlp_kernel<<<N_EDGES / 128, 256, 0, stream>>>(x, WbF, b_res, W_out, b_out, Win4, e);
    segsum_kernel<<<(N_EDGES + 255) / 256, 256, 0, stream>>>(e, ids, segsum);
    norm_kernel<<<(N_EDGES + 255) / 256, 256, 0, stream>>>(e, ids, segsum, out);
}

// Round 8
// 965.255 us; speedup vs baseline: 3.9643x; 2.0994x over previous
//
#include <hip/hip_runtime.h>
#include <stdint.h>

#define N_EDGES 2000000
#define NUM_SEG 500000
#define HID 128
#define NBLK 4
#define NWG 512          // persistent workgroups: 2 per CU
#define NCHUNK 15625     // N_EDGES / 128

typedef __attribute__((ext_vector_type(8))) unsigned short ushort8;
typedef __attribute__((ext_vector_type(8))) __bf16 bf16x8;
typedef __attribute__((ext_vector_type(4))) float float4v;
typedef __attribute__((ext_vector_type(2))) float float2v;
typedef __attribute__((ext_vector_type(2))) uint32_t uint2v;

__device__ inline unsigned short f32_to_bf16(float f) {
    return __builtin_bit_cast(unsigned short, (__bf16)f);   // native cvt, RNE
}

__device__ inline uint32_t pack_bf16(float lo, float hi) {
#if __has_builtin(__builtin_amdgcn_cvt_pk_bf16_f32)
    typedef __attribute__((ext_vector_type(2))) __bf16 bf16x2;
    bf16x2 r = __builtin_amdgcn_cvt_pk_bf16_f32(lo, hi);
    return __builtin_bit_cast(uint32_t, r);
#else
    return (uint32_t)f32_to_bf16(lo) | ((uint32_t)f32_to_bf16(hi) << 16);
#endif
}

// ---- prep: WbF[blk] = bf16(W_res*rms_w) in A-FRAGMENT ORDER:
//   i = blk*16384 + (kt*8+ft)*512 + lane*8 + j -> W'[m=ft*16+(lane&15)][k=kt*32+(lane>>4)*8+j]
// Also packs Win4[f] = {W_in[f][0..2], b_in[f]} and zero-fills segsum.
__global__ void prep_kernel(const float* __restrict__ W_res,
                            const float* __restrict__ rms_w,
                            const float* __restrict__ W_in,
                            const float* __restrict__ b_in,
                            unsigned short* __restrict__ WbF,
                            float* __restrict__ Win4,
                            float* __restrict__ segsum) {
    int i = blockIdx.x * 256 + threadIdx.x;
    if (i < 65536) {
        int blk = i >> 14;
        int r = i & 16383;
        int j = r & 7, lane = (r >> 3) & 63, ft = (r >> 9) & 7, kt = r >> 12;
        int cc = lane & 15, qq = lane >> 4;
        int row = ft * 16 + cc;
        int k = kt * 32 + qq * 8 + j;
        WbF[i] = f32_to_bf16(W_res[blk * 16384 + row * HID + k] * rms_w[blk * HID + k]);
    } else if (i < 65536 + 128) {
        int f = i - 65536;
        Win4[f * 4 + 0] = W_in[f * 3 + 0];
        Win4[f * 4 + 1] = W_in[f * 3 + 1];
        Win4[f * 4 + 2] = W_in[f * 3 + 2];
        Win4[f * 4 + 3] = b_in[f];
    } else {
        int s = i - 65536 - 128;
        if (s < NUM_SEG) segsum[s] = 0.0f;
    }
}

// ---- fused MLP (persistent): 512 wg x ~31 chunks of 128 rows. Per chunk: 4 waves x
// 32 rows, h in D[f][r] registers, W in LDS (register wreg prefetch cycling mod 4),
// hnF B-frags 8 KB/wave. Next chunk's x prefetched into regs after stage-1, parked
// into the ping-pong xs buffer at blk 1, made visible by the chunk-end barrier.
__global__ __launch_bounds__(256, 2)
void mlp_kernel(const float* __restrict__ x,           // [N,3]
                const unsigned short* __restrict__ WbF,// [4,16384] bf16 A-frag order
                const float* __restrict__ b_res,       // [4,128]
                const float* __restrict__ W_out,       // [128]
                const float* __restrict__ b_out,       // [1]
                const float* __restrict__ Win4g,       // [128,4] = {w0,w1,w2,b_in}
                float* __restrict__ e) {               // [N] = exp(logit)
    __shared__ __align__(16) unsigned short WsF[16384];   // 32 KB, A-frag order
    __shared__ __align__(16) unsigned short hnF[16384];   // 32 KB, 8 KB/wave B-frags
    __shared__ __align__(16) float4v Win4s[128];          // 2 KB
    __shared__ __align__(16) float xs[768];               // 3 KB, ping-pong 2x384

    const int t = threadIdx.x;
    const int wave = t >> 6;
    const int lane = t & 63;
    const int q = lane >> 4;   // quad within wave
    const int c = lane & 15;   // lane within quad

    // prefetch W for blk 0 (lane-linear)
    ushort8 wreg[8];
    #pragma unroll
    for (int i = 0; i < 8; ++i)
        wreg[i] = *(const ushort8*)&WbF[(i * 256 + t) * 8];

    for (int i = t; i < 384; i += 256) xs[i] = x[(long)blockIdx.x * 384 + i];
    if (t < 128) Win4s[t] = ((const float4v*)Win4g)[t];
    __syncthreads();

    // hnF: 8 slots/wave (kt*2+rt), 512 shorts each; per-wave private
    const int whbase = wave * 4096 + (q >> 1) * 128 + c * 8 + (q & 1) * 4;  // write base
    const int rbase = wave * 4096 + lane * 8;                                // read base
    const float bo = b_out[0];

    int cur = 0;
    for (int chunk = blockIdx.x; chunk < NCHUNK; chunk += NWG) {
        const long rowbase = (long)chunk * 128;
        const int xoff = cur * 384;

        // ---- stage 1: h0[f][r] = W_in[f].x[r] + b_in[f]
        float4v h[8][2];   // [ft][rt]; f = ft*16+q*4+reg, r = wave*32+rt*16+c
        {
            float xr[2][3];
            #pragma unroll
            for (int rt = 0; rt < 2; ++rt)
                #pragma unroll
                for (int k = 0; k < 3; ++k)
                    xr[rt][k] = xs[xoff + (wave * 32 + rt * 16 + c) * 3 + k];
            #pragma unroll
            for (int ft = 0; ft < 8; ++ft)
                #pragma unroll
                for (int reg = 0; reg < 4; ++reg) {
                    float4v wb = Win4s[ft * 16 + q * 4 + reg];
                    #pragma unroll
                    for (int rt = 0; rt < 2; ++rt)
                        h[ft][rt][reg] = wb.w + xr[rt][0] * wb.x + xr[rt][1] * wb.y + xr[rt][2] * wb.z;
                }
        }

        // issue next chunk's x load (lands during blk0; parked to LDS at blk1)
        const int nchunk = chunk + NWG;
        const bool have_next = (nchunk < NCHUNK) && (t < 192);
        float2v xnext = {0.0f, 0.0f};
        if (have_next)
            xnext = *(const float2v*)(x + (long)nchunk * 384 + t * 2);

        #pragma unroll
        for (int blk = 0; blk < NBLK; ++blk) {
            // publish this block's W to LDS (lane-contiguous, conflict-free)
            #pragma unroll
            for (int i = 0; i < 8; ++i)
                *(ushort8*)&WsF[(i * 256 + t) * 8] = wreg[i];
            __syncthreads();
            // prefetch next block's W (cycles mod 4 so chunk boundaries pipeline)
            {
                const unsigned short* Wn = WbF + ((blk + 1) & 3) * 16384;
                #pragma unroll
                for (int i = 0; i < 8; ++i)
                    wreg[i] = *(const ushort8*)&Wn[(i * 256 + t) * 8];
            }

            if (blk == 1 && have_next)   // park next x into the other xs buffer
                *(float2v*)&xs[(cur ^ 1) * 384 + t * 2] = xnext;

            // write raw h as packed bf16 into B-frag-order LDS (16 x ds_write_b64)
            #pragma unroll
            for (int ft = 0; ft < 8; ++ft) {
                const int foff = (ft >> 1) * 1024 + (ft & 1) * 256;
                #pragma unroll
                for (int rt = 0; rt < 2; ++rt) {
                    uint2v v;
                    v.x = pack_bf16(h[ft][rt][0], h[ft][rt][1]);
                    v.y = pack_bf16(h[ft][rt][2], h[ft][rt][3]);
                    *(uint2v*)&hnF[whbase + foff + rt * 512] = v;
                }
            }

            // rmsnorm scale per row (row = rt*16+c)
            float rs[2];
            #pragma unroll
            for (int rt = 0; rt < 2; ++rt) {
                float ss = 0.0f;
                #pragma unroll
                for (int ft = 0; ft < 8; ++ft)
                    #pragma unroll
                    for (int reg = 0; reg < 4; ++reg) { float vv = h[ft][rt][reg]; ss += vv * vv; }
                ss += __shfl_xor(ss, 16, 64);
                ss += __shfl_xor(ss, 32, 64);
                rs[rt] = rsqrtf(ss * (1.0f / 128.0f) + 1.1920929e-7f);
            }

            // MFMA: acc[ft][rt], kt=0 peeled with C=0
            float4v acc[8][2];
            {
                bf16x8 b0 = __builtin_bit_cast(bf16x8, *(const ushort8*)&hnF[rbase + 0 * 512]);
                bf16x8 b1 = __builtin_bit_cast(bf16x8, *(const ushort8*)&hnF[rbase + 1 * 512]);
                const float4v zero4 = {0.0f, 0.0f, 0.0f, 0.0f};
                #pragma unroll
                for (int ft = 0; ft < 8; ++ft) {
                    bf16x8 a = __builtin_bit_cast(bf16x8, *(const ushort8*)&WsF[ft * 512 + lane * 8]);
                    acc[ft][0] = __builtin_amdgcn_mfma_f32_16x16x32_bf16(a, b0, zero4, 0, 0, 0);
                    acc[ft][1] = __builtin_amdgcn_mfma_f32_16x16x32_bf16(a, b1, zero4, 0, 0, 0);
                }
            }
            #pragma unroll
            for (int kt = 1; kt < 4; ++kt) {
                bf16x8 b0 = __builtin_bit_cast(bf16x8, *(const ushort8*)&hnF[rbase + (kt * 2 + 0) * 512]);
                bf16x8 b1 = __builtin_bit_cast(bf16x8, *(const ushort8*)&hnF[rbase + (kt * 2 + 1) * 512]);
                #pragma unroll
                for (int ft = 0; ft < 8; ++ft) {
                    bf16x8 a = __builtin_bit_cast(bf16x8,
                        *(const ushort8*)&WsF[(kt * 8 + ft) * 512 + lane * 8]);
                    acc[ft][0] = __builtin_amdgcn_mfma_f32_16x16x32_bf16(a, b0, acc[ft][0], 0, 0, 0);
                    acc[ft][1] = __builtin_amdgcn_mfma_f32_16x16x32_bf16(a, b1, acc[ft][1], 0, 0, 0);
                }
            }

            // epilogue: h += relu(rs[rt]*acc + b_res[f])
            {
                const float4v* br4 = (const float4v*)(b_res + blk * HID);
                #pragma unroll
                for (int ft = 0; ft < 8; ++ft) {
                    float4v bb = br4[ft * 4 + q];
                    #pragma unroll
                    for (int rt = 0; rt < 2; ++rt)
                        #pragma unroll
                        for (int reg = 0; reg < 4; ++reg)
                            h[ft][rt][reg] += fmaxf(fmaf(rs[rt], acc[ft][rt][reg], bb[reg]), 0.0f);
                }
            }
            __syncthreads();   // WsF readers done; (at blk3) also publishes xs[nxt]
        }

        // ---- output head: e[r] = exp(h[.][r] . W_out + b_out)
        const float4v* wo4 = (const float4v*)W_out;
        float s[2] = {0.0f, 0.0f};
        #pragma unroll
        for (int ft = 0; ft < 8; ++ft) {
            float4v w = wo4[ft * 4 + q];
            #pragma unroll
            for (int rt = 0; rt < 2; ++rt)
                #pragma unroll
                for (int reg = 0; reg < 4; ++reg)
                    s[rt] += h[ft][rt][reg] * w[reg];
        }
        #pragma unroll
        for (int rt = 0; rt < 2; ++rt) {
            s[rt] += __shfl_xor(s[rt], 16, 64);
            s[rt] += __shfl_xor(s[rt], 32, 64);
        }
        if (q == 0) {
            #pragma unroll
            for (int rt = 0; rt < 2; ++rt)
                e[rowbase + wave * 32 + rt * 16 + c] = __expf(s[rt] + bo);
        }
        cur ^= 1;
    }
}

// ---- segment sum of e (sorted ids): wave-level segmented scan, tail lanes atomicAdd
__global__ void segsum_kernel(const float* __restrict__ e, const int* __restrict__ ids,
                              float* __restrict__ segsum) {
    int i = blockIdx.x * 256 + threadIdx.x;
    int lane = threadIdx.x & 63;
    float v = 0.0f; int id = -1;
    if (i < N_EDGES) { v = e[i]; id = ids[i]; }
    #pragma unroll
    for (int d = 1; d < 64; d <<= 1) {
        float ov = __shfl_up(v, d, 64);
        int oid = __shfl_up(id, d, 64);
        if (lane >= d && oid == id) v += ov;
    }
    int nid = __shfl_down(id, 1, 64);
    bool tail = (lane == 63) || (nid != id);
    if (id >= 0 && tail) atomicAdd(&segsum[id], v);
}

__global__ void norm_kernel(const float* __restrict__ e, const int* __restrict__ ids,
                            const float* __restrict__ segsum, float* __restrict__ out) {
    int i = blockIdx.x * 256 + threadIdx.x;
    if (i < N_EDGES) out[i] = e[i] / segsum[ids[i]];
}

extern "C" void kernel_launch(void* const* d_in, const int* in_sizes, int n_in,
                              void* d_out, int out_size, void* d_ws, size_t ws_size,
                              hipStream_t stream) {
    const float* x      = (const float*)d_in[0];
    const int*   ids    = (const int*)d_in[1];
    const float* W_in   = (const float*)d_in[2];
    const float* b_in   = (const float*)d_in[3];
    const float* rms_w  = (const float*)d_in[4];
    const float* W_res  = (const float*)d_in[5];
    const float* b_res  = (const float*)d_in[6];
    const float* W_out  = (const float*)d_in[7];
    const float* b_out  = (const float*)d_in[8];
    float* out = (float*)d_out;

    char* ws = (char*)d_ws;
    unsigned short* WbF = (unsigned short*)ws;                 // 131072 B
    float* Win4   = (float*)(ws + 131072);                     // 2048 B
    float* e      = (float*)(ws + 131072 + 2048);              // 8,000,000 B
    float* segsum = (float*)(ws + 131072 + 2048 + 8000000);    // 2,000,000 B

    int prep_items = 65536 + 128 + NUM_SEG;
    prep_kernel<<<(prep_items + 255) / 256, 256, 0, stream>>>(W_res, rms_w, W_in, b_in,
                                                              WbF, Win4, segsum);
    mlp_kernel<<<NWG, 256, 0, stream>>>(x, WbF, b_res, W_out, b_out, Win4, e);
    segsum_kernel<<<(N_EDGES + 255) / 256, 256, 0, stream>>>(e, ids, segsum);
    norm_kernel<<<(N_EDGES + 255) / 256, 256, 0, stream>>>(e, ids, segsum, out);
}

// Round 9
// 562.887 us; speedup vs baseline: 6.7980x; 1.7148x over previous
//
#include <hip/hip_runtime.h>
#include <stdint.h>

#define N_EDGES 2000000
#define NUM_SEG 500000
#define HID 128
#define NBLK 4

typedef __attribute__((ext_vector_type(8))) unsigned short ushort8;
typedef __attribute__((ext_vector_type(8))) __bf16 bf16x8;
typedef __attribute__((ext_vector_type(4))) float float4v;
typedef __attribute__((ext_vector_type(2))) uint32_t uint2v;

__device__ inline unsigned short f32_to_bf16(float f) {
    return __builtin_bit_cast(unsigned short, (__bf16)f);   // native cvt, RNE
}

__device__ inline uint32_t pack_bf16(float lo, float hi) {
#if __has_builtin(__builtin_amdgcn_cvt_pk_bf16_f32)
    typedef __attribute__((ext_vector_type(2))) __bf16 bf16x2;
    bf16x2 r = __builtin_amdgcn_cvt_pk_bf16_f32(lo, hi);
    return __builtin_bit_cast(uint32_t, r);
#else
    return (uint32_t)f32_to_bf16(lo) | ((uint32_t)f32_to_bf16(hi) << 16);
#endif
}

// ---- prep: WbF[blk] = bf16(W_res*rms_w) in A-FRAGMENT ORDER:
//   i = blk*16384 + (kt*8+ft)*512 + lane*8 + j -> W'[m=ft*16+(lane&15)][k=kt*32+(lane>>4)*8+j]
// Also packs Win4[f] = {W_in[f][0..2], b_in[f]} and zero-fills segsum.
__global__ void prep_kernel(const float* __restrict__ W_res,
                            const float* __restrict__ rms_w,
                            const float* __restrict__ W_in,
                            const float* __restrict__ b_in,
                            unsigned short* __restrict__ WbF,
                            float* __restrict__ Win4,
                            float* __restrict__ segsum) {
    int i = blockIdx.x * 256 + threadIdx.x;
    if (i < 65536) {
        int blk = i >> 14;
        int r = i & 16383;
        int j = r & 7, lane = (r >> 3) & 63, ft = (r >> 9) & 7, kt = r >> 12;
        int cc = lane & 15, qq = lane >> 4;
        int row = ft * 16 + cc;
        int k = kt * 32 + qq * 8 + j;
        WbF[i] = f32_to_bf16(W_res[blk * 16384 + row * HID + k] * rms_w[blk * HID + k]);
    } else if (i < 65536 + 128) {
        int f = i - 65536;
        Win4[f * 4 + 0] = W_in[f * 3 + 0];
        Win4[f * 4 + 1] = W_in[f * 3 + 1];
        Win4[f * 4 + 2] = W_in[f * 3 + 2];
        Win4[f * 4 + 3] = b_in[f];
    } else {
        int s = i - 65536 - 128;
        if (s < NUM_SEG) segsum[s] = 0.0f;
    }
}

// ---- fused MLP: 128 rows/wg, 4 waves x 32 rows, h in D[f][r] layout registers.
// W staged K-half at a time via async global_load_lds (Wlo/Whi ping-pong across the
// two per-block barriers). hnF is 4KB/wave, slots reused between K-halves (safe:
// intra-wave LDS ops are in-order, hnF is per-wave private).
// launch_bounds (256,2): the proven no-spill budget. (256,3) spilled h — R5/R6/R7.
__global__ __launch_bounds__(256, 2)
void mlp_kernel(const float* __restrict__ x,           // [N,3]
                const unsigned short* __restrict__ WbF,// [4,16384] bf16 A-frag order
                const float* __restrict__ b_res,       // [4,128]
                const float* __restrict__ W_out,       // [128]
                const float* __restrict__ b_out,       // [1]
                const float* __restrict__ Win4g,       // [128,4] = {w0,w1,w2,b_in}
                float* __restrict__ e) {               // [N] = exp(logit)
    __shared__ __align__(16) unsigned short Wlo[8192];  // 16 KB: kt 0,1 A-frags
    __shared__ __align__(16) unsigned short Whi[8192];  // 16 KB: kt 2,3 A-frags
    __shared__ __align__(16) unsigned short hnF[8192];  // 16 KB: 4 KB/wave B-frags
    __shared__ __align__(16) float4v Win4s[128];        // 2 KB
    __shared__ float xs[384];                           // 1.5 KB

    const int t = threadIdx.x;
    const int wave = t >> 6;
    const int lane = t & 63;
    const int q = lane >> 4;   // quad within wave
    const int c = lane & 15;   // lane within quad
    const long rowbase = (long)blockIdx.x * 128;

    // async 16KB W-half load: 4 waves x 4 issues x 1KB (lds dest = uniform base + lane*16B)
    #define LOAD_HALF(gbase, ldsarr)                                                      \
        {                                                                                 \
            const unsigned short* _g = (gbase);                                           \
            _Pragma("unroll")                                                             \
            for (int _i = 0; _i < 4; ++_i) {                                              \
                __builtin_amdgcn_global_load_lds(                                         \
                    (const __attribute__((address_space(1))) uint32_t*)                   \
                        (_g + (wave * 4 + _i) * 512 + lane * 8),                          \
                    (__attribute__((address_space(3))) uint32_t*)                         \
                        (&(ldsarr)[(wave * 4 + _i) * 512]),                               \
                    16, 0, 0);                                                            \
            }                                                                             \
        }

    LOAD_HALF(WbF, Wlo);                              // blk0 lo in flight
    for (int i = t; i < 384; i += 256) xs[i] = x[rowbase * 3 + i];
    if (t < 128) Win4s[t] = ((const float4v*)Win4g)[t];
    __syncthreads();                                  // drains lo0 + xs + Win4s
    LOAD_HALF(WbF + 8192, Whi);                       // blk0 hi in flight during stage-1

    // ---- stage 1: h0[f][r] = W_in[f].x[r] + b_in[f]
    float4v h[8][2];   // [ft][rt]; f = ft*16+q*4+reg, r = wave*32+rt*16+c
    {
        float xr[2][3];
        #pragma unroll
        for (int rt = 0; rt < 2; ++rt)
            #pragma unroll
            for (int k = 0; k < 3; ++k)
                xr[rt][k] = xs[(wave * 32 + rt * 16 + c) * 3 + k];
        #pragma unroll
        for (int ft = 0; ft < 8; ++ft)
            #pragma unroll
            for (int reg = 0; reg < 4; ++reg) {
                float4v wb = Win4s[ft * 16 + q * 4 + reg];
                #pragma unroll
                for (int rt = 0; rt < 2; ++rt)
                    h[ft][rt][reg] = wb.w + xr[rt][0] * wb.x + xr[rt][1] * wb.y + xr[rt][2] * wb.z;
            }
    }

    // hnF: 4 slots/wave ((kt&1)*2+rt), 512 shorts each, reused between K-halves
    const int whbase = wave * 2048 + (q >> 1) * 128 + c * 8 + (q & 1) * 4;  // write base
    const int rbase  = wave * 2048 + lane * 8;                               // read base

    #pragma unroll 1
    for (int blk = 0; blk < NBLK; ++blk) {
        float4v acc[8][2];
        float rs[2];

        // ======== LO half: kt 0,1  (B-frags built from ft 0..3) ========
        #pragma unroll
        for (int ft = 0; ft < 4; ++ft) {
            const int foff = ((ft >> 1) & 1) * 1024 + (ft & 1) * 256;
            #pragma unroll
            for (int rt = 0; rt < 2; ++rt) {
                uint2v v;
                v.x = pack_bf16(h[ft][rt][0], h[ft][rt][1]);
                v.y = pack_bf16(h[ft][rt][2], h[ft][rt][3]);
                *(uint2v*)&hnF[whbase + foff + rt * 512] = v;
            }
        }
        // rmsnorm scale (off the LDS critical path)
        #pragma unroll
        for (int rt = 0; rt < 2; ++rt) {
            float ss = 0.0f;
            #pragma unroll
            for (int ft = 0; ft < 8; ++ft)
                #pragma unroll
                for (int reg = 0; reg < 4; ++reg) { float vv = h[ft][rt][reg]; ss += vv * vv; }
            ss += __shfl_xor(ss, 16, 64);
            ss += __shfl_xor(ss, 32, 64);
            rs[rt] = rsqrtf(ss * (1.0f / 128.0f) + 1.1920929e-7f);
        }
        // MFMA kt=0 (C=0 peel) and kt=1 from Wlo
        {
            bf16x8 b0 = __builtin_bit_cast(bf16x8, *(const ushort8*)&hnF[rbase + 0 * 512]);
            bf16x8 b1 = __builtin_bit_cast(bf16x8, *(const ushort8*)&hnF[rbase + 1 * 512]);
            const float4v zero4 = {0.0f, 0.0f, 0.0f, 0.0f};
            #pragma unroll
            for (int ft = 0; ft < 8; ++ft) {
                bf16x8 a = __builtin_bit_cast(bf16x8, *(const ushort8*)&Wlo[ft * 512 + lane * 8]);
                acc[ft][0] = __builtin_amdgcn_mfma_f32_16x16x32_bf16(a, b0, zero4, 0, 0, 0);
                acc[ft][1] = __builtin_amdgcn_mfma_f32_16x16x32_bf16(a, b1, zero4, 0, 0, 0);
            }
            bf16x8 b2 = __builtin_bit_cast(bf16x8, *(const ushort8*)&hnF[rbase + 2 * 512]);
            bf16x8 b3 = __builtin_bit_cast(bf16x8, *(const ushort8*)&hnF[rbase + 3 * 512]);
            #pragma unroll
            for (int ft = 0; ft < 8; ++ft) {
                bf16x8 a = __builtin_bit_cast(bf16x8,
                    *(const ushort8*)&Wlo[(8 + ft) * 512 + lane * 8]);
                acc[ft][0] = __builtin_amdgcn_mfma_f32_16x16x32_bf16(a, b2, acc[ft][0], 0, 0, 0);
                acc[ft][1] = __builtin_amdgcn_mfma_f32_16x16x32_bf16(a, b3, acc[ft][1], 0, 0, 0);
            }
        }
        __syncthreads();   // Wlo readers done; drains Whi(blk) issued one half earlier
        if (blk < NBLK - 1) LOAD_HALF(WbF + (blk + 1) * 16384, Wlo);

        // ======== HI half: kt 2,3  (B-frags from ft 4..7, slots reused) ========
        #pragma unroll
        for (int ft = 4; ft < 8; ++ft) {
            const int foff = ((ft >> 1) & 1) * 1024 + (ft & 1) * 256;
            #pragma unroll
            for (int rt = 0; rt < 2; ++rt) {
                uint2v v;
                v.x = pack_bf16(h[ft][rt][0], h[ft][rt][1]);
                v.y = pack_bf16(h[ft][rt][2], h[ft][rt][3]);
                *(uint2v*)&hnF[whbase + foff + rt * 512] = v;
            }
        }
        {
            bf16x8 b0 = __builtin_bit_cast(bf16x8, *(const ushort8*)&hnF[rbase + 0 * 512]);
            bf16x8 b1 = __builtin_bit_cast(bf16x8, *(const ushort8*)&hnF[rbase + 1 * 512]);
            #pragma unroll
            for (int ft = 0; ft < 8; ++ft) {
                bf16x8 a = __builtin_bit_cast(bf16x8, *(const ushort8*)&Whi[ft * 512 + lane * 8]);
                acc[ft][0] = __builtin_amdgcn_mfma_f32_16x16x32_bf16(a, b0, acc[ft][0], 0, 0, 0);
                acc[ft][1] = __builtin_amdgcn_mfma_f32_16x16x32_bf16(a, b1, acc[ft][1], 0, 0, 0);
            }
            bf16x8 b2 = __builtin_bit_cast(bf16x8, *(const ushort8*)&hnF[rbase + 2 * 512]);
            bf16x8 b3 = __builtin_bit_cast(bf16x8, *(const ushort8*)&hnF[rbase + 3 * 512]);
            #pragma unroll
            for (int ft = 0; ft < 8; ++ft) {
                bf16x8 a = __builtin_bit_cast(bf16x8,
                    *(const ushort8*)&Whi[(8 + ft) * 512 + lane * 8]);
                acc[ft][0] = __builtin_amdgcn_mfma_f32_16x16x32_bf16(a, b2, acc[ft][0], 0, 0, 0);
                acc[ft][1] = __builtin_amdgcn_mfma_f32_16x16x32_bf16(a, b3, acc[ft][1], 0, 0, 0);
            }
        }
        // epilogue: h += relu(rs[rt]*acc + b_res[f])
        {
            const float4v* br4 = (const float4v*)(b_res + blk * HID);
            #pragma unroll
            for (int ft = 0; ft < 8; ++ft) {
                float4v bb = br4[ft * 4 + q];
                #pragma unroll
                for (int rt = 0; rt < 2; ++rt)
                    #pragma unroll
                    for (int reg = 0; reg < 4; ++reg)
                        h[ft][rt][reg] += fmaxf(fmaf(rs[rt], acc[ft][rt][reg], bb[reg]), 0.0f);
            }
        }
        __syncthreads();   // Whi readers done; drains Wlo(blk+1) issued one half earlier
        if (blk < NBLK - 1) LOAD_HALF(WbF + (blk + 1) * 16384 + 8192, Whi);
    }

    // ---- output head: e[r] = exp(h[.][r] . W_out + b_out)
    const float bo = b_out[0];
    const float4v* wo4 = (const float4v*)W_out;
    float s[2] = {0.0f, 0.0f};
    #pragma unroll
    for (int ft = 0; ft < 8; ++ft) {
        float4v w = wo4[ft * 4 + q];
        #pragma unroll
        for (int rt = 0; rt < 2; ++rt)
            #pragma unroll
            for (int reg = 0; reg < 4; ++reg)
                s[rt] += h[ft][rt][reg] * w[reg];
    }
    #pragma unroll
    for (int rt = 0; rt < 2; ++rt) {
        s[rt] += __shfl_xor(s[rt], 16, 64);
        s[rt] += __shfl_xor(s[rt], 32, 64);
    }
    if (q == 0) {
        #pragma unroll
        for (int rt = 0; rt < 2; ++rt)
            e[rowbase + wave * 32 + rt * 16 + c] = __expf(s[rt] + bo);
    }
}

// ---- segment sum of e (sorted ids): wave-level segmented scan, tail lanes atomicAdd
__global__ void segsum_kernel(const float* __restrict__ e, const int* __restrict__ ids,
                              float* __restrict__ segsum) {
    int i = blockIdx.x * 256 + threadIdx.x;
    int lane = threadIdx.x & 63;
    float v = 0.0f; int id = -1;
    if (i < N_EDGES) { v = e[i]; id = ids[i]; }
    #pragma unroll
    for (int d = 1; d < 64; d <<= 1) {
        float ov = __shfl_up(v, d, 64);
        int oid = __shfl_up(id, d, 64);
        if (lane >= d && oid == id) v += ov;
    }
    int nid = __shfl_down(id, 1, 64);
    bool tail = (lane == 63) || (nid != id);
    if (id >= 0 && tail) atomicAdd(&segsum[id], v);
}

__global__ void norm_kernel(const float* __restrict__ e, const int* __restrict__ ids,
                            const float* __restrict__ segsum, float* __restrict__ out) {
    int i = blockIdx.x * 256 + threadIdx.x;
    if (i < N_EDGES) out[i] = e[i] / segsum[ids[i]];
}

extern "C" void kernel_launch(void* const* d_in, const int* in_sizes, int n_in,
                              void* d_out, int out_size, void* d_ws, size_t ws_size,
                              hipStream_t stream) {
    const float* x      = (const float*)d_in[0];
    const int*   ids    = (const int*)d_in[1];
    const float* W_in   = (const float*)d_in[2];
    const float* b_in   = (const float*)d_in[3];
    const float* rms_w  = (const float*)d_in[4];
    const float* W_res  = (const float*)d_in[5];
    const float* b_res  = (const float*)d_in[6];
    const float* W_out  = (const float*)d_in[7];
    const float* b_out  = (const float*)d_in[8];
    float* out = (float*)d_out;

    char* ws = (char*)d_ws;
    unsigned short* WbF = (unsigned short*)ws;                 // 131072 B
    float* Win4   = (float*)(ws + 131072);                     // 2048 B
    float* e      = (float*)(ws + 131072 + 2048);              // 8,000,000 B
    float* segsum = (float*)(ws + 131072 + 2048 + 8000000);    // 2,000,000 B

    int prep_items = 65536 + 128 + NUM_SEG;
    prep_kernel<<<(prep_items + 255) / 256, 256, 0, stream>>>(W_res, rms_w, W_in, b_in,
                                                              WbF, Win4, segsum);
    mlp_kernel<<<N_EDGES / 128, 256, 0, stream>>>(x, WbF, b_res, W_out, b_out, Win4, e);
    segsum_kernel<<<(N_EDGES + 255) / 256, 256, 0, stream>>>(e, ids, segsum);
    norm_kernel<<<(N_EDGES + 255) / 256, 256, 0, stream>>>(e, ids, segsum, out);
}